// Round 16
// baseline (136.577 us; speedup 1.0000x reference)
//
#include <hip/hip_runtime.h>
#include <math.h>

#define T_LEN      24000
#define TS         448           // samples per slice
#define NSLICE     54            // 54*448 = 24192 >= 24000 (slice 53: 256 valid)
#define W_LEN      81
#define HALF_W     40
#define NK         21
#define MAXORD     10
#define NIMG_TOTAL 1561
#define NROUNDS    25            // ceil(1561/64)
#define FS_F       48000.0f
#define C_F        343.0f
#define FS_OVER_C  (48000.0f / 343.0f)
#define PI_F       3.14159265358979323846f
#define INV_4PI_F  0.07957747154594767f
#define LOG2_BETA  (-0.15200309344504997f)   // log2(0.9)
#define NEG_SLOPE  0.01f

// d_ws layout: [B*T_LEN floats rir staging][B rows of (32 f2 hdr + 1568 f2 params)]
#define HDR_F2     32
#define PAR_CAP    1568
#define ROW_F2     (HDR_F2 + PAR_CAP)        // 1600 float2 = 12800 B/row

// ---- compile-time table of valid image triples ----
struct Table { unsigned int e[NROUNDS * 64]; };
constexpr Table make_table() {
    Table t{};
    int n = 0;
    for (int kx = 0; kx < NK; ++kx)
        for (int ky = 0; ky < NK; ++ky)
            for (int kz = 0; kz < NK; ++kz) {
                int ax = kx >= MAXORD ? kx - MAXORD : MAXORD - kx;
                int ay = ky >= MAXORD ? ky - MAXORD : MAXORD - ky;
                int az = kz >= MAXORD ? kz - MAXORD : MAXORD - kz;
                int order = ax + ay + az;
                if (order <= MAXORD)
                    t.e[n++] = (unsigned)((order << 15) | (kx << 10) | (ky << 5) | kz);
            }
    for (int i = n; i < NROUNDS * 64; ++i) t.e[i] = t.e[n - 1];  // pad (masked)
    return t;
}
__constant__ Table g_tbl = make_table();

#define PROCESS(aU, dU)                                                        \
    do {                                                                       \
        float t0b  = floorf(dU);                                              \
        float frac = (dU) - t0b;                                              \
        float sp   = __sinf(PI_F * frac);                                     \
        float pv   = sg * sp;                                                 \
        int   idx  = (int)t0b - HALF_W + lane - lo;                           \
        float x1p  = c1p - PI_F * frac;                                       \
        float sv1  = (x1p == 0.0f) ? 1.0f : pv * __builtin_amdgcn_rcpf(x1p);  \
        if ((unsigned)idx < (unsigned)nout)                                   \
            atomicAdd(&rirw[idx], (aU) * sv1 * hw1);                          \
        if (lane < 17) {                                                      \
            int idx2 = idx + 64;                                              \
            float sv2 = pv * __builtin_amdgcn_rcpf(x1p + 64.0f * PI_F);       \
            if ((unsigned)idx2 < (unsigned)nout)                              \
                atomicAdd(&rirw[idx2], (aU) * sv2 * hw2);                     \
        }                                                                      \
    } while (0)

// ============ Kernel 1: per-row MLP + geometry + bin-sorted params ==========
__global__ __launch_bounds__(64)
void rir_prep_kernel(const float* __restrict__ g_in,
                     const float* __restrict__ W1, const float* __restrict__ b1,
                     const float* __restrict__ W2, const float* __restrict__ b2,
                     const float* __restrict__ W3, const float* __restrict__ b3,
                     float2* __restrict__ pws, float* __restrict__ out_origin)
{
    __shared__ float dsq[3 * NK];
    __shared__ float h1[30], h2[20], zb[9], sm_in[22], rms[9];
    __shared__ int counts[NSLICE], offs[NSLICE + 1], cursor[NSLICE];

    const int lane = threadIdx.x;
    const int b    = blockIdx.x;

    if (lane < NSLICE) counts[lane] = 0;

    if (lane < 22) sm_in[lane] = g_in[b * 22 + lane];
    if (lane < 30) {
        float a = b1[lane];
        const float* wp = W1 + lane * 22;
        #pragma unroll
        for (int i = 0; i < 22; ++i) a += sm_in[i] * wp[i];
        h1[lane] = (a >= 0.0f) ? a : NEG_SLOPE * a;
    }
    if (lane < 20) {
        float a = b2[lane];
        const float* wp = W2 + lane * 30;
        #pragma unroll
        for (int i = 0; i < 30; ++i) a += h1[i] * wp[i];
        h2[lane] = (a >= 0.0f) ? a : NEG_SLOPE * a;
    }
    if (lane < 9) {
        float a = b3[lane];
        const float* wp = W3 + lane * 20;
        #pragma unroll
        for (int i = 0; i < 20; ++i) a += h2[i] * wp[i];
        zb[lane] = 1.0f / (1.0f + __expf(-a));
    }
    if (lane < 3) {
        float room = zb[lane] * 20.0f;
        rms[lane]     = room;
        rms[3 + lane] = zb[3 + lane] * room;   // mic
        rms[6 + lane] = zb[6 + lane] * room;   // src
    }
    if (lane == 0) {
        float dx = rms[3] - rms[6], dy = rms[4] - rms[7], dz = rms[5] - rms[8];
        out_origin[b] = 40.0f + FS_F * sqrtf(dx * dx + dy * dy + dz * dz) / C_F;
    }
    if (lane < 3 * NK) {
        int a  = lane / NK;
        int kk = (lane - a * NK) - MAXORD;
        float L = rms[a], src = rms[6 + a];
        float img = ((kk & 1) == 0) ? (float)kk * L + src : (float)(kk + 1) * L - src;
        float diff = img - rms[3 + a];
        dsq[lane] = diff * diff;
    }

    // pass 1: count images per bin
    for (int r = 0; r < NROUNDS; ++r) {
        int gi = r * 64 + lane;
        unsigned e = g_tbl.e[gi];
        int kzi = e & 31, kyi = (e >> 5) & 31, kxi = (e >> 10) & 31;
        float d   = sqrtf(dsq[kxi] + dsq[NK + kyi] + dsq[2 * NK + kzi]);
        float dly = 40.0f + d * FS_OVER_C;
        int   t0  = (int)floorf(dly);
        bool live = (gi < NIMG_TOTAL) && (t0 - HALF_W < T_LEN);
        if (live) atomicAdd(&counts[min(t0 / TS, NSLICE - 1)], 1);
    }

    if (lane == 0) {
        int acc = 0;
        for (int s = 0; s < NSLICE; ++s) { offs[s] = acc; acc += counts[s]; }
        offs[NSLICE] = acc;
    }
    if (lane < NSLICE) cursor[lane] = 0;

    float2* row  = pws + (size_t)b * ROW_F2;
    float2* prow = row + HDR_F2;

    // pass 2: recompute params, scatter bin-sorted
    for (int r = 0; r < NROUNDS; ++r) {
        int gi = r * 64 + lane;
        unsigned e = g_tbl.e[gi];
        int kzi = e & 31, kyi = (e >> 5) & 31, kxi = (e >> 10) & 31, order = (int)(e >> 15);
        float d   = sqrtf(dsq[kxi] + dsq[NK + kyi] + dsq[2 * NK + kzi]);
        float dly = 40.0f + d * FS_OVER_C;
        int   t0  = (int)floorf(dly);
        bool live = (gi < NIMG_TOTAL) && (t0 - HALF_W < T_LEN);
        if (live) {
            float amp = exp2f((float)order * LOG2_BETA) * INV_4PI_F
                        * __builtin_amdgcn_rcpf(fmaxf(d, 0.001f));
            int bin  = min(t0 / TS, NSLICE - 1);
            int rank = offs[bin] + atomicAdd(&cursor[bin], 1);
            prow[rank] = make_float2(amp, dly);
        }
    }

    int* hdr = (int*)row;
    if (lane <= NSLICE) hdr[lane] = offs[lane];
}

// ============ Kernel 2: slice scatter -> WS (not d_out) =====================
__global__ __launch_bounds__(64)
void rir_scatter_ws_kernel(const float2* __restrict__ pws,
                           float* __restrict__ ws_rir)
{
    __shared__ __align__(16) float rirw[TS];

    const int lane = threadIdx.x;
    const int s    = blockIdx.x;
    const int b    = blockIdx.y;
    const int lo   = s * TS;
    const int nout = min(TS, T_LEN - lo);

    const float2* row  = pws + (size_t)b * ROW_F2;
    const float2* prow = row + HDR_F2;
    const int*    hdr  = (const int*)row;

    const int s0    = (s > 0) ? s - 1 : 0;
    const int s1    = (s < NSLICE - 1) ? s + 1 : NSLICE - 1;
    const int start = hdr[s0];
    const int end   = hdr[s1 + 1];

    float4* rir4 = (float4*)rirw;
    rir4[lane] = make_float4(0.f, 0.f, 0.f, 0.f);
    if (lane < TS / 4 - 64) rir4[64 + lane] = make_float4(0.f, 0.f, 0.f, 0.f);

    const float c1p = PI_F * (float)(lane - HALF_W);
    const float hw1 = 0.5f - 0.5f * __cosf((float)lane * (2.0f * PI_F / 80.0f));
    const float hw2 = 0.5f - 0.5f * __cosf((float)(lane + 64) * (2.0f * PI_F / 80.0f));
    const float sg  = (lane & 1) ? 1.0f : -1.0f;

    const float lof = (float)(lo - HALF_W);
    const float hif = (float)(lo + nout - 1 + HALF_W);

    for (int i0 = start + lane; i0 - lane < end; i0 += 64) {
        const bool inr = (i0 < end);
        float2 p = prow[inr ? i0 : start];
        float t0f = floorf(p.y);
        bool hit  = inr && (t0f >= lof) && (t0f <= hif);
        float ampv = p.x, dlyv = p.y;

        unsigned long long mask = __ballot(hit);
        while (mask) {
            int l0 = __builtin_ctzll(mask); mask &= mask - 1;
            bool have1 = (mask != 0);
            int l1 = have1 ? __builtin_ctzll(mask) : l0;
            if (have1) mask &= mask - 1;

            float a0 = __shfl(ampv, l0), d0 = __shfl(dlyv, l0);
            float a1 = __shfl(ampv, l1), d1 = __shfl(dlyv, l1);
            PROCESS(a0, d0);
            if (have1) PROCESS(a1, d1);
        }
    }

    const int n4 = nout / 4;
    float4* out4 = (float4*)(ws_rir + (size_t)b * T_LEN + lo);
    out4[lane] = rir4[lane];
    if (lane + 64 < n4) out4[lane + 64] = rir4[lane + 64];
}

// ============ Kernel 3: pure streaming copy WS -> d_out =====================
__global__ __launch_bounds__(256)
void rir_copy_kernel(const float4* __restrict__ src, float4* __restrict__ dst,
                     int n4)
{
    const int stride = gridDim.x * 256;
    for (int i = blockIdx.x * 256 + threadIdx.x; i < n4; i += stride) {
        float4 v = src[i];
        __builtin_nontemporal_store(v.x, &dst[i].x);
        __builtin_nontemporal_store(v.y, &dst[i].y);
        __builtin_nontemporal_store(v.z, &dst[i].z);
        __builtin_nontemporal_store(v.w, &dst[i].w);
    }
}

// ============ Fallback: R15 scatter direct to d_out =========================
__global__ __launch_bounds__(64)
void rir_scatter_kernel(const float2* __restrict__ pws, float* __restrict__ out_rir)
{
    __shared__ __align__(16) float rirw[TS];

    const int lane = threadIdx.x;
    const int s    = blockIdx.x;
    const int b    = blockIdx.y;
    const int lo   = s * TS;
    const int nout = min(TS, T_LEN - lo);

    const float2* row  = pws + (size_t)b * ROW_F2;
    const float2* prow = row + HDR_F2;
    const int*    hdr  = (const int*)row;

    const int s0    = (s > 0) ? s - 1 : 0;
    const int s1    = (s < NSLICE - 1) ? s + 1 : NSLICE - 1;
    const int start = hdr[s0];
    const int end   = hdr[s1 + 1];

    float4* rir4 = (float4*)rirw;
    rir4[lane] = make_float4(0.f, 0.f, 0.f, 0.f);
    if (lane < TS / 4 - 64) rir4[64 + lane] = make_float4(0.f, 0.f, 0.f, 0.f);

    const float c1p = PI_F * (float)(lane - HALF_W);
    const float hw1 = 0.5f - 0.5f * __cosf((float)lane * (2.0f * PI_F / 80.0f));
    const float hw2 = 0.5f - 0.5f * __cosf((float)(lane + 64) * (2.0f * PI_F / 80.0f));
    const float sg  = (lane & 1) ? 1.0f : -1.0f;

    const float lof = (float)(lo - HALF_W);
    const float hif = (float)(lo + nout - 1 + HALF_W);

    for (int i0 = start + lane; i0 - lane < end; i0 += 64) {
        const bool inr = (i0 < end);
        float2 p = prow[inr ? i0 : start];
        float t0f = floorf(p.y);
        bool hit  = inr && (t0f >= lof) && (t0f <= hif);
        float ampv = p.x, dlyv = p.y;

        unsigned long long mask = __ballot(hit);
        while (mask) {
            int l0 = __builtin_ctzll(mask); mask &= mask - 1;
            bool have1 = (mask != 0);
            int l1 = have1 ? __builtin_ctzll(mask) : l0;
            if (have1) mask &= mask - 1;

            float a0 = __shfl(ampv, l0), d0 = __shfl(dlyv, l0);
            float a1 = __shfl(ampv, l1), d1 = __shfl(dlyv, l1);
            PROCESS(a0, d0);
            if (have1) PROCESS(a1, d1);
        }
    }

    const int n4 = nout / 4;
    float4* out4 = (float4*)(out_rir + (size_t)b * T_LEN + lo);
    out4[lane] = rir4[lane];
    if (lane + 64 < n4) out4[lane + 64] = rir4[lane + 64];
}

extern "C" void kernel_launch(void* const* d_in, const int* in_sizes, int n_in,
                              void* d_out, int out_size, void* d_ws, size_t ws_size,
                              hipStream_t stream) {
    const float* g_in = (const float*)d_in[0];
    const float* W1   = (const float*)d_in[1];
    const float* b1   = (const float*)d_in[2];
    const float* W2   = (const float*)d_in[3];
    const float* b2   = (const float*)d_in[4];
    const float* W3   = (const float*)d_in[5];
    const float* b3   = (const float*)d_in[6];

    const int B = in_sizes[0] / 22;

    float* out_rir    = (float*)d_out;
    float* out_origin = out_rir + (size_t)B * T_LEN;

    const size_t rir_floats = (size_t)B * T_LEN;
    const size_t need_full  = rir_floats * 4 + (size_t)B * ROW_F2 * 8;  // ~13.9 MB
    const size_t need_par   = (size_t)B * ROW_F2 * 8;                   // ~1.64 MB

    if (ws_size >= need_full) {
        float*  ws_rir = (float*)d_ws;
        float2* pws    = (float2*)((char*)d_ws + rir_floats * 4);
        rir_prep_kernel<<<B, 64, 0, stream>>>(
            g_in, W1, b1, W2, b2, W3, b3, pws, out_origin);
        dim3 grid2(NSLICE, B);
        rir_scatter_ws_kernel<<<grid2, 64, 0, stream>>>(pws, ws_rir);
        const int n4 = (int)(rir_floats / 4);
        rir_copy_kernel<<<2048, 256, 0, stream>>>(
            (const float4*)ws_rir, (float4*)out_rir, n4);
    } else if (ws_size >= need_par) {
        float2* pws = (float2*)d_ws;
        rir_prep_kernel<<<B, 64, 0, stream>>>(
            g_in, W1, b1, W2, b2, W3, b3, pws, out_origin);
        dim3 grid2(NSLICE, B);
        rir_scatter_kernel<<<grid2, 64, 0, stream>>>(pws, out_rir);
    }
    // (harness guarantees a generous d_ws; need_par path covers the rest)
}

// Round 17
// 113.898 us; speedup vs baseline: 1.1991x; 1.1991x over previous
//
#include <hip/hip_runtime.h>
#include <math.h>

#define T_LEN      24000
#define TS         448           // bin width for delay-sorting
#define NSLICE     54
#define W_LEN      81
#define HALF_W     40
#define NK         21
#define MAXORD     10
#define NIMG_TOTAL 1561
#define NROUNDS    25            // ceil(1561/64)
#define NCHUNK     25            // 64-image chunks per row
#define BUFCAP     2560          // LDS window floats (10 KB): span81 <= BUFCAP -> LDS path
#define NZB        2048          // zeroing blocks fused into prep dispatch
#define FS_F       48000.0f
#define C_F        343.0f
#define FS_OVER_C  (48000.0f / 343.0f)
#define PI_F       3.14159265358979323846f
#define HSTEP      (2.0f * PI_F / 80.0f)
#define INV_4PI_F  0.07957747154594767f
#define LOG2_BETA  (-0.15200309344504997f)   // log2(0.9)
#define NEG_SLOPE  0.01f

// ws: B rows of (32 float2 hdr + 1568 float2 sorted params) = 12800 B/row
#define HDR_F2     32
#define PAR_CAP    1568
#define ROW_F2     (HDR_F2 + PAR_CAP)

struct Table { unsigned int e[NROUNDS * 64]; };
constexpr Table make_table() {
    Table t{};
    int n = 0;
    for (int kx = 0; kx < NK; ++kx)
        for (int ky = 0; ky < NK; ++ky)
            for (int kz = 0; kz < NK; ++kz) {
                int ax = kx >= MAXORD ? kx - MAXORD : MAXORD - kx;
                int ay = ky >= MAXORD ? ky - MAXORD : MAXORD - ky;
                int az = kz >= MAXORD ? kz - MAXORD : MAXORD - kz;
                int order = ax + ay + az;
                if (order <= MAXORD)
                    t.e[n++] = (unsigned)((order << 15) | (kx << 10) | (ky << 5) | kz);
            }
    for (int i = n; i < NROUNDS * 64; ++i) t.e[i] = t.e[n - 1];
    return t;
}
__constant__ Table g_tbl = make_table();

// ===== Kernel 1: fused {per-row prep (bin-sorted params)} + {zero d_out} ====
__global__ __launch_bounds__(64)
void prep_zero_kernel(const float* __restrict__ g_in,
                      const float* __restrict__ W1, const float* __restrict__ b1,
                      const float* __restrict__ W2, const float* __restrict__ b2,
                      const float* __restrict__ W3, const float* __restrict__ b3,
                      float2* __restrict__ pws, float* __restrict__ out_rir,
                      float* __restrict__ out_origin, int B)
{
    const int blk  = blockIdx.x;
    const int lane = threadIdx.x;

    if (blk >= B) {
        // ---- streaming zero of the rir output region ----
        const size_t n4     = (size_t)B * T_LEN / 4;
        const size_t stride = (size_t)NZB * 64;
        float4* o4 = (float4*)out_rir;
        for (size_t i = (size_t)(blk - B) * 64 + lane; i < n4; i += stride)
            o4[i] = make_float4(0.f, 0.f, 0.f, 0.f);
        return;
    }

    __shared__ float dsq[3 * NK];
    __shared__ float h1[30], h2[20], zb[9], sm_in[22], rms[9];
    __shared__ int counts[NSLICE], offs[NSLICE + 1], cursor[NSLICE];

    const int b = blk;
    if (lane < NSLICE) counts[lane] = 0;

    if (lane < 22) sm_in[lane] = g_in[b * 22 + lane];
    if (lane < 30) {
        float a = b1[lane];
        const float* wp = W1 + lane * 22;
        #pragma unroll
        for (int i = 0; i < 22; ++i) a += sm_in[i] * wp[i];
        h1[lane] = (a >= 0.0f) ? a : NEG_SLOPE * a;
    }
    if (lane < 20) {
        float a = b2[lane];
        const float* wp = W2 + lane * 30;
        #pragma unroll
        for (int i = 0; i < 30; ++i) a += h1[i] * wp[i];
        h2[lane] = (a >= 0.0f) ? a : NEG_SLOPE * a;
    }
    if (lane < 9) {
        float a = b3[lane];
        const float* wp = W3 + lane * 20;
        #pragma unroll
        for (int i = 0; i < 20; ++i) a += h2[i] * wp[i];
        zb[lane] = 1.0f / (1.0f + __expf(-a));
    }
    if (lane < 3) {
        float room = zb[lane] * 20.0f;
        rms[lane]     = room;
        rms[3 + lane] = zb[3 + lane] * room;   // mic
        rms[6 + lane] = zb[6 + lane] * room;   // src
    }
    if (lane == 0) {
        float dx = rms[3] - rms[6], dy = rms[4] - rms[7], dz = rms[5] - rms[8];
        out_origin[b] = 40.0f + FS_F * sqrtf(dx * dx + dy * dy + dz * dz) / C_F;
    }
    if (lane < 3 * NK) {
        int a  = lane / NK;
        int kk = (lane - a * NK) - MAXORD;
        float L = rms[a], src = rms[6 + a];
        float img = ((kk & 1) == 0) ? (float)kk * L + src : (float)(kk + 1) * L - src;
        float diff = img - rms[3 + a];
        dsq[lane] = diff * diff;
    }

    // pass 1: bin counts (bin = t0/TS -> delay-sorted output)
    for (int r = 0; r < NROUNDS; ++r) {
        int gi = r * 64 + lane;
        unsigned e = g_tbl.e[gi];
        int kzi = e & 31, kyi = (e >> 5) & 31, kxi = (e >> 10) & 31;
        float d   = sqrtf(dsq[kxi] + dsq[NK + kyi] + dsq[2 * NK + kzi]);
        float dly = 40.0f + d * FS_OVER_C;
        int   t0  = (int)floorf(dly);
        bool live = (gi < NIMG_TOTAL) && (t0 - HALF_W < T_LEN);
        if (live) atomicAdd(&counts[min(t0 / TS, NSLICE - 1)], 1);
    }
    if (lane == 0) {
        int acc = 0;
        for (int s = 0; s < NSLICE; ++s) { offs[s] = acc; acc += counts[s]; }
        offs[NSLICE] = acc;
    }
    if (lane < NSLICE) cursor[lane] = 0;

    float2* row  = pws + (size_t)b * ROW_F2;
    float2* prow = row + HDR_F2;

    // pass 2: scatter bin-sorted params
    for (int r = 0; r < NROUNDS; ++r) {
        int gi = r * 64 + lane;
        unsigned e = g_tbl.e[gi];
        int kzi = e & 31, kyi = (e >> 5) & 31, kxi = (e >> 10) & 31, order = (int)(e >> 15);
        float d   = sqrtf(dsq[kxi] + dsq[NK + kyi] + dsq[2 * NK + kzi]);
        float dly = 40.0f + d * FS_OVER_C;
        int   t0  = (int)floorf(dly);
        bool live = (gi < NIMG_TOTAL) && (t0 - HALF_W < T_LEN);
        if (live) {
            float amp = exp2f((float)order * LOG2_BETA) * INV_4PI_F
                        * __builtin_amdgcn_rcpf(fmaxf(d, 0.001f));
            int bin  = min(t0 / TS, NSLICE - 1);
            int rank = offs[bin] + atomicAdd(&cursor[bin], 1);
            prow[rank] = make_float2(amp, dly);
        }
    }

    // pad tail so every chunk slot is initialized (amp=0, delay sentinel)
    const int total = offs[NSLICE];
    for (int i = total + lane; i < NCHUNK * 64; i += 64)
        prow[i] = make_float2(0.0f, 1.0e9f);

    int* hdr = (int*)row;
    if (lane <= NSLICE) hdr[lane] = offs[lane];
}

// ===== Kernel 2: uniform 64-image chunk scatter (lane-per-image) ============
__global__ __launch_bounds__(64)
void scatter_chunk_kernel(const float2* __restrict__ pws,
                          float* __restrict__ out_rir)
{
    __shared__ __align__(16) float buf[BUFCAP];

    const int lane = threadIdx.x;
    const int c    = blockIdx.x;
    const int b    = blockIdx.y;

    const float2* prow = pws + (size_t)b * ROW_F2 + HDR_F2;
    const float2  p    = prow[c * 64 + lane];
    const bool    live = (p.y < 1.0e8f);
    if (__ballot(live) == 0ull) return;         // all-pad chunk

    const float t0f = floorf(p.y);
    const int   t0  = (int)t0f;
    const float frac = p.y - t0f;
    const float sp   = __sinf(PI_F * frac);
    const float amp  = p.x;

    // wave min/max of t0 over live lanes -> chunk delay span
    int tmn = live ? t0 : 0x7fffffff;
    int tmx = live ? t0 : (int)0x80000000;
    #pragma unroll
    for (int m = 32; m; m >>= 1) {
        tmn = min(tmn, __shfl_xor(tmn, m));
        tmx = max(tmx, __shfl_xor(tmx, m));
    }
    const int span81 = tmx - tmn + W_LEN;

    float* outb = out_rir + (size_t)b * T_LEN;

    if (span81 <= BUFCAP) {
        // ---- LDS window path (dense chunks; pileups land here) ----
        for (int i = lane; i < span81; i += 64) buf[i] = 0.0f;  // 1-wave: in-order DS

        if (live) {
            float nf  = -(float)HALF_W - frac;   // (j-40) - frac, exact +1.0 steps
            float pv  = -amp * sp;               // sign for n=-40 (even)
            float arg = 0.0f;                    // hann angle j * 2pi/80
            int   idx = t0 - tmn;                // buf index of tap j=0 (+HALF_W offset folded)
            #pragma unroll 9
            for (int j = 0; j < W_LEN; ++j) {
                float hj = 0.5f - 0.5f * __cosf(arg);
                float sv = (nf == 0.0f) ? amp : pv * __builtin_amdgcn_rcpf(PI_F * nf);
                atomicAdd(&buf[idx], sv * hj);
                nf += 1.0f; pv = -pv; arg += HSTEP; ++idx;
            }
        }

        // flush nonzeros with native f32 global atomics
        const int gbase = tmn - HALF_W;          // >= 0 (t0 >= 40)
        for (int o = lane; o < span81; o += 64) {
            float v = buf[o];
            int   g = gbase + o;
            if (v != 0.0f && g < T_LEN)
                unsafeAtomicAdd(&outb[g], v);
        }
    } else {
        // ---- wide-span (sparse) chunk: direct global atomics ----
        if (live) {
            float nf  = -(float)HALF_W - frac;
            float pv  = -amp * sp;
            float arg = 0.0f;
            int   idx = t0 - HALF_W;
            #pragma unroll 9
            for (int j = 0; j < W_LEN; ++j) {
                float hj = 0.5f - 0.5f * __cosf(arg);
                float sv = (nf == 0.0f) ? amp : pv * __builtin_amdgcn_rcpf(PI_F * nf);
                if ((unsigned)idx < (unsigned)T_LEN)
                    unsafeAtomicAdd(&outb[idx], sv * hj);
                nf += 1.0f; pv = -pv; arg += HSTEP; ++idx;
            }
        }
    }
}

// ===== Fallback: R10 single-kernel (ws too small) ===========================
#define FTS 448
#define FNSLICE 54
__global__ __launch_bounds__(64)
void rir_wave_kernel(const float* __restrict__ g_in,
                     const float* __restrict__ W1, const float* __restrict__ b1,
                     const float* __restrict__ W2, const float* __restrict__ b2,
                     const float* __restrict__ W3, const float* __restrict__ b3,
                     float* __restrict__ out_rir, float* __restrict__ out_origin)
{
    __shared__ __align__(16) float rirw[FTS];
    __shared__ float dsq[3 * NK];
    __shared__ float h1[30], h2[20], zb[9], sm_in[22], rms[9];

    const int lane = threadIdx.x;
    const int s    = blockIdx.x;
    const int b    = blockIdx.y;
    const int lo   = s * FTS;
    const int nout = min(FTS, T_LEN - lo);

    float4* rir4 = (float4*)rirw;
    rir4[lane] = make_float4(0.f, 0.f, 0.f, 0.f);
    if (lane < FTS / 4 - 64) rir4[64 + lane] = make_float4(0.f, 0.f, 0.f, 0.f);

    const float c1p = PI_F * (float)(lane - HALF_W);
    const float hw1 = 0.5f - 0.5f * __cosf((float)lane * HSTEP);
    const float hw2 = 0.5f - 0.5f * __cosf((float)(lane + 64) * HSTEP);
    const float sg  = (lane & 1) ? 1.0f : -1.0f;

    if (lane < 22) sm_in[lane] = g_in[b * 22 + lane];
    if (lane < 30) {
        float a = b1[lane];
        const float* wp = W1 + lane * 22;
        #pragma unroll
        for (int i = 0; i < 22; ++i) a += sm_in[i] * wp[i];
        h1[lane] = (a >= 0.0f) ? a : NEG_SLOPE * a;
    }
    if (lane < 20) {
        float a = b2[lane];
        const float* wp = W2 + lane * 30;
        #pragma unroll
        for (int i = 0; i < 30; ++i) a += h1[i] * wp[i];
        h2[lane] = (a >= 0.0f) ? a : NEG_SLOPE * a;
    }
    if (lane < 9) {
        float a = b3[lane];
        const float* wp = W3 + lane * 20;
        #pragma unroll
        for (int i = 0; i < 20; ++i) a += h2[i] * wp[i];
        zb[lane] = 1.0f / (1.0f + __expf(-a));
    }
    if (lane < 3) {
        float room = zb[lane] * 20.0f;
        rms[lane]     = room;
        rms[3 + lane] = zb[3 + lane] * room;
        rms[6 + lane] = zb[6 + lane] * room;
    }
    if (lane == 0 && s == 0) {
        float dx = rms[3] - rms[6], dy = rms[4] - rms[7], dz = rms[5] - rms[8];
        out_origin[b] = 40.0f + FS_F * sqrtf(dx * dx + dy * dy + dz * dz) / C_F;
    }
    if (lane < 3 * NK) {
        int a  = lane / NK;
        int kk = (lane - a * NK) - MAXORD;
        float L = rms[a], src = rms[6 + a];
        float img = ((kk & 1) == 0) ? (float)kk * L + src : (float)(kk + 1) * L - src;
        float diff = img - rms[3 + a];
        dsq[lane] = diff * diff;
    }

    const float lof = (float)(lo - HALF_W);
    const float hif = (float)(lo + nout - 1 + HALF_W);

    for (int r = 0; r < NROUNDS; ++r) {
        unsigned e = g_tbl.e[r * 64 + lane];
        bool live  = (r * 64 + lane) < NIMG_TOTAL;
        int kzi = e & 31, kyi = (e >> 5) & 31, kxi = (e >> 10) & 31, order = (int)(e >> 15);
        float d    = sqrtf(dsq[kxi] + dsq[NK + kyi] + dsq[2 * NK + kzi]);
        float dlyv = 40.0f + d * FS_OVER_C;
        float t0f  = floorf(dlyv);
        float ampv = exp2f((float)order * LOG2_BETA) * INV_4PI_F
                     * __builtin_amdgcn_rcpf(fmaxf(d, 0.001f));
        bool hit = live && (t0f >= lof) && (t0f <= hif);

        unsigned long long mask = __ballot(hit);
        while (mask) {
            int l0 = __builtin_ctzll(mask); mask &= mask - 1;
            float a0 = __shfl(ampv, l0), d0 = __shfl(dlyv, l0);
            float t0b  = floorf(d0);
            float frac = d0 - t0b;
            float sp   = __sinf(PI_F * frac);
            float pv   = sg * sp;
            int   idx  = (int)t0b - HALF_W + lane - lo;
            float x1p  = c1p - PI_F * frac;
            float sv1  = (x1p == 0.0f) ? 1.0f : pv * __builtin_amdgcn_rcpf(x1p);
            if ((unsigned)idx < (unsigned)nout)
                atomicAdd(&rirw[idx], a0 * sv1 * hw1);
            if (lane < 17) {
                int idx2 = idx + 64;
                float sv2 = pv * __builtin_amdgcn_rcpf(x1p + 64.0f * PI_F);
                if ((unsigned)idx2 < (unsigned)nout)
                    atomicAdd(&rirw[idx2], a0 * sv2 * hw2);
            }
        }
    }

    const int n4 = nout / 4;
    float4* out4 = (float4*)(out_rir + (size_t)b * T_LEN + lo);
    out4[lane] = rir4[lane];
    if (lane + 64 < n4) out4[lane + 64] = rir4[lane + 64];
}

extern "C" void kernel_launch(void* const* d_in, const int* in_sizes, int n_in,
                              void* d_out, int out_size, void* d_ws, size_t ws_size,
                              hipStream_t stream) {
    const float* g_in = (const float*)d_in[0];
    const float* W1   = (const float*)d_in[1];
    const float* b1   = (const float*)d_in[2];
    const float* W2   = (const float*)d_in[3];
    const float* b2   = (const float*)d_in[4];
    const float* W3   = (const float*)d_in[5];
    const float* b3   = (const float*)d_in[6];

    const int B = in_sizes[0] / 22;

    float* out_rir    = (float*)d_out;
    float* out_origin = out_rir + (size_t)B * T_LEN;

    const size_t need_ws = (size_t)B * ROW_F2 * sizeof(float2);   // ~1.64 MB

    if (ws_size >= need_ws) {
        float2* pws = (float2*)d_ws;
        prep_zero_kernel<<<B + NZB, 64, 0, stream>>>(
            g_in, W1, b1, W2, b2, W3, b3, pws, out_rir, out_origin, B);
        dim3 grid2(NCHUNK, B);
        scatter_chunk_kernel<<<grid2, 64, 0, stream>>>(pws, out_rir);
    } else {
        dim3 grid(FNSLICE, B);
        rir_wave_kernel<<<grid, 64, 0, stream>>>(
            g_in, W1, b1, W2, b2, W3, b3, out_rir, out_origin);
    }
}